// Round 6
// baseline (740.568 us; speedup 1.0000x reference)
//
#include <hip/hip_runtime.h>

// Replicate GEMM-family (Eigen/XLA-CPU/BLAS) fp32 semantics for xc:
// per-(token,codeword) sequential FMA chain over d=0..63, ascending.
// x2/c2 keep numpy pairwise 8-accumulator scalar scheme.
// No implicit contraction anywhere.
#pragma clang fp contract(off)

#define NSUB 16
#define CBK  1024
#define SDIM 64
#define EMB  1024
#define NTOK 16384

#define TOKB 256      // tokens per block (1 per thread; lane = token)
#define KCH  128      // codewords staged per LDS chunk
#define CPAD 68       // padded row stride (floats)

__device__ __forceinline__ float fmul(float a, float b) { return __fmul_rn(a, b); }
__device__ __forceinline__ float fadd(float a, float b) { return __fadd_rn(a, b); }
__device__ __forceinline__ float fsub(float a, float b) { return __fsub_rn(a, b); }

// numpy np.sum pairwise replica, scalar 8-accumulator path (n=64):
// products come from a separately-rounded (v*v) temp, summed mul-free.
__device__ __forceinline__ float np_pairwise_sq64(const float* v) {
    float r[8];
    #pragma unroll
    for (int j = 0; j < 8; ++j) r[j] = fmul(v[j], v[j]);
    #pragma unroll
    for (int b = 1; b < 8; ++b) {
        #pragma unroll
        for (int j = 0; j < 8; ++j)
            r[j] = fadd(r[j], fmul(v[b * 8 + j], v[b * 8 + j]));
    }
    return fadd(fadd(fadd(r[0], r[1]), fadd(r[2], r[3])),
                fadd(fadd(r[4], r[5]), fadd(r[6], r[7])));
}

__global__ __launch_bounds__(256, 4)
void pq_np_kernel(const float* __restrict__ emb,
                  const float* __restrict__ cb,
                  float* __restrict__ qout,
                  float* __restrict__ iout)
{
    __shared__ float cs[KCH][CPAD];
    __shared__ float c2s[KCH];
    __shared__ int   bestk_s[TOKB];

    const int m    = blockIdx.y;
    const int tok0 = blockIdx.x * TOKB;
    const int t    = threadIdx.x;

    // ---- my token's subvector into registers ----
    float xr[64];
    {
        const float* xsrc = emb + (size_t)(tok0 + t) * EMB + m * SDIM;
        #pragma unroll
        for (int i = 0; i < 16; ++i) {
            float4 v = *(const float4*)(xsrc + 4 * i);
            xr[4*i+0] = v.x; xr[4*i+1] = v.y; xr[4*i+2] = v.z; xr[4*i+3] = v.w;
        }
    }
    const float x2v = np_pairwise_sq64(xr);

    float rmin = 3.4e38f;
    int   rk   = 0;

    for (int ch = 0; ch < CBK / KCH; ++ch) {
        __syncthreads();
        // ---- stage 128 codeword rows (coalesced) ----
        {
            const int row = t >> 1, half = t & 1;
            const float* src = cb + ((size_t)m * CBK + ch * KCH + row) * SDIM + half * 32;
            float* dstrow = &cs[row][half * 32];
            #pragma unroll
            for (int i = 0; i < 8; ++i) {
                float4 v = *(const float4*)(src + 4 * i);
                dstrow[4*i+0] = v.x; dstrow[4*i+1] = v.y;
                dstrow[4*i+2] = v.z; dstrow[4*i+3] = v.w;
            }
        }
        __syncthreads();
        if (t < KCH) c2s[t] = np_pairwise_sq64(&cs[t][0]);
        __syncthreads();

        // ---- scan chunk: lane = token; 2 codeword rows in flight for ILP ----
        #pragma unroll 2
        for (int rrow = 0; rrow < KCH; ++rrow) {
            const float* crow = &cs[rrow][0];
            // GEMM-family semantics: xc = sequential FMA chain, d ascending
            float acc = 0.f;
            #pragma unroll
            for (int i = 0; i < 16; ++i) {
                float4 c4 = *(const float4*)(crow + 4 * i);
                acc = __fmaf_rn(xr[4*i+0], c4.x, acc);
                acc = __fmaf_rn(xr[4*i+1], c4.y, acc);
                acc = __fmaf_rn(xr[4*i+2], c4.z, acc);
                acc = __fmaf_rn(xr[4*i+3], c4.w, acc);
            }
            // dist2 = (x2 - 2.0*xc) + c2, left-to-right
            const float t1   = fsub(x2v, fmul(2.0f, acc));
            const float dist = fadd(t1, c2s[rrow]);
            const int k = ch * KCH + rrow;   // ascending; strict < keeps first
            if (dist < rmin) { rmin = dist; rk = k; }
        }
    }

    bestk_s[t] = rk;
    iout[(size_t)(tok0 + t) * NSUB + m] = (float)rk;  // buffer read back as f32
    __syncthreads();

    // ---- gather winning codewords (coalesced) ----
    #pragma unroll
    for (int p = 0; p < 4; ++p) {
        const int tokL = p * 64 + (t >> 2);
        const int part = t & 3;
        const int bk = bestk_s[tokL];
        const float* src = cb + ((size_t)m * CBK + bk) * SDIM + part * 16;
        float* dst = qout + (size_t)(tok0 + tokL) * EMB + m * SDIM + part * 16;
        #pragma unroll
        for (int i = 0; i < 4; ++i)
            *(float4*)(dst + 4 * i) = *(const float4*)(src + 4 * i);
    }
}

extern "C" void kernel_launch(void* const* d_in, const int* in_sizes, int n_in,
                              void* d_out, int out_size, void* d_ws, size_t ws_size,
                              hipStream_t stream) {
    const float* emb = (const float*)d_in[0];   // [8,2048,1024] f32
    const float* cb  = (const float*)d_in[1];   // [16,1024,64] f32
    float* qout = (float*)d_out;                              // [N, EMB] f32
    float* iout = (float*)d_out + (size_t)NTOK * EMB;         // [N, 16] as f32

    dim3 grid(NTOK / TOKB, NSUB);
    pq_np_kernel<<<grid, 256, 0, stream>>>(emb, cb, qout, iout);
}

// Round 7
// 648.647 us; speedup vs baseline: 1.1417x; 1.1417x over previous
//
#include <hip/hip_runtime.h>

// Correctness contract (verified R6, absmax=0):
//   xc   = sequential __fmaf_rn chain over d=0..63 ascending
//   x2,c2= numpy pairwise scalar 8-accumulator scheme
//   dist = fl(fl(x2 - 2*xc) + c2), argmin first-occurrence
// Fast pass may use any arithmetic; near-ties (gap<=MARGIN) fall back to the
// bit-exact chain. No implicit contraction anywhere.
#pragma clang fp contract(off)

#define NSUB 16
#define CBK  1024
#define SDIM 64
#define EMB  1024
#define NTOK 16384

#define TOKT 128
#define CWT  128
#define MARGIN 1e-2f   // >> 1.5e-3 worst-case |fast_score - chain_score| bound

__device__ __forceinline__ float fmul(float a, float b) { return __fmul_rn(a, b); }
__device__ __forceinline__ float fadd(float a, float b) { return __fadd_rn(a, b); }
__device__ __forceinline__ float fsub(float a, float b) { return __fsub_rn(a, b); }

// numpy pairwise replica (scalar 8-accumulator, n=64), strided access.
__device__ __forceinline__ float np_sq64(const float* v, int stride) {
    float r[8];
    #pragma unroll
    for (int j = 0; j < 8; ++j) { float e = v[j * stride]; r[j] = fmul(e, e); }
    #pragma unroll
    for (int b = 1; b < 8; ++b) {
        #pragma unroll
        for (int j = 0; j < 8; ++j) {
            float e = v[(b * 8 + j) * stride];
            r[j] = fadd(r[j], fmul(e, e));
        }
    }
    return fadd(fadd(fadd(r[0], r[1]), fadd(r[2], r[3])),
                fadd(fadd(r[4], r[5]), fadd(r[6], r[7])));
}

__global__ __launch_bounds__(256, 2)
void pq_twophase_kernel(const float* __restrict__ emb,
                        const float* __restrict__ cb,
                        float* __restrict__ qout,
                        float* __restrict__ iout)
{
    __shared__ float As[SDIM][TOKT];   // 32 KiB [d][token]; intact for fallback
    __shared__ float Bs[SDIM][CWT];    // 32 KiB [d][cw]; reused as merge scratch
    __shared__ float C2[CBK];          // replica ||c||^2
    __shared__ float x2s[TOKT];        // replica ||x||^2
    __shared__ float red_v[256];
    __shared__ int   red_k[256];
    __shared__ int   bestk_s[TOKT];
    __shared__ int   flag_s[TOKT];
    __shared__ int   cnt_s;

    const int m    = blockIdx.y;
    const int tok0 = blockIdx.x * TOKT;
    const int t    = threadIdx.x;
    const int tx   = t & 15;
    const int ty   = t >> 4;

    if (t == 0) cnt_s = 0;

    // ---- stage A (128 tokens x 64 dims) transposed ----
    {
        const int tok = t >> 1, d0 = (t & 1) * 32;
        const float* src = emb + (size_t)(tok0 + tok) * EMB + m * SDIM + d0;
        #pragma unroll
        for (int i = 0; i < 8; ++i) {
            float4 v = *(const float4*)(src + 4 * i);
            As[d0 + 4*i + 0][tok] = v.x; As[d0 + 4*i + 1][tok] = v.y;
            As[d0 + 4*i + 2][tok] = v.z; As[d0 + 4*i + 3][tok] = v.w;
        }
    }
    // ---- replica ||c||^2 for all 1024 rows (L2-hot) ----
    #pragma unroll
    for (int j = 0; j < 4; ++j) {
        const int c = t * 4 + j;
        C2[c] = np_sq64(cb + ((size_t)m * CBK + c) * SDIM, 1);
    }
    __syncthreads();
    if (t < TOKT) x2s[t] = np_sq64(&As[0][t], TOKT);  // conflict-free column read

    // ---- pass 1: fast 8x8 register GEMM + per-token top-2 ----
    float rmin1[8], rmin2[8]; int ridx1[8];
    #pragma unroll
    for (int i = 0; i < 8; ++i) { rmin1[i] = 3.4e38f; rmin2[i] = 3.4e38f; ridx1[i] = 0; }

    for (int kc = 0; kc < CBK; kc += CWT) {
        const int cw = t >> 1, d0 = (t & 1) * 32;
        const float* src = cb + ((size_t)m * CBK + kc + cw) * SDIM + d0;
        float4 v[8];
        #pragma unroll
        for (int i = 0; i < 8; ++i) v[i] = *(const float4*)(src + 4 * i);
        __syncthreads();
        #pragma unroll
        for (int i = 0; i < 8; ++i) {
            Bs[d0 + 4*i + 0][cw] = v[i].x; Bs[d0 + 4*i + 1][cw] = v[i].y;
            Bs[d0 + 4*i + 2][cw] = v[i].z; Bs[d0 + 4*i + 3][cw] = v[i].w;
        }
        __syncthreads();

        float acc[8][8];
        #pragma unroll
        for (int i = 0; i < 8; ++i)
            #pragma unroll
            for (int j = 0; j < 8; ++j) acc[i][j] = 0.f;

        #pragma unroll 4
        for (int d = 0; d < SDIM; ++d) {
            float4 a0 = *(const float4*)&As[d][ty * 8];
            float4 a1 = *(const float4*)&As[d][ty * 8 + 4];
            float4 b0 = *(const float4*)&Bs[d][tx * 8];
            float4 b1 = *(const float4*)&Bs[d][tx * 8 + 4];
            float av[8] = {a0.x,a0.y,a0.z,a0.w,a1.x,a1.y,a1.z,a1.w};
            float bv[8] = {b0.x,b0.y,b0.z,b0.w,b1.x,b1.y,b1.z,b1.w};
            #pragma unroll
            for (int i = 0; i < 8; ++i)
                #pragma unroll
                for (int j = 0; j < 8; ++j)
                    acc[i][j] = __fmaf_rn(av[i], bv[j], acc[i][j]);
        }

        const int kbase = kc + tx * 8;
        float4 c20 = *(const float4*)&C2[kbase];
        float4 c21 = *(const float4*)&C2[kbase + 4];
        float c2v[8] = {c20.x,c20.y,c20.z,c20.w,c21.x,c21.y,c21.z,c21.w};
        #pragma unroll
        for (int i = 0; i < 8; ++i) {
            #pragma unroll
            for (int j = 0; j < 8; ++j) {
                float s = __fmaf_rn(-2.f, acc[i][j], c2v[j]);
                if (s < rmin1[i]) { rmin2[i] = rmin1[i]; rmin1[i] = s; ridx1[i] = kbase + j; }
                else if (s < rmin2[i]) { rmin2[i] = s; }
            }
        }
    }

    __syncthreads();
    // ---- top-2 merge across tx; scratch in Bs (stride 17) ----
    float* redv1 = &Bs[0][0];
    int*   redk1 = (int*)(&Bs[0][0] + 2176);
    float* redv2 = &Bs[0][0] + 4352;
    #pragma unroll
    for (int i = 0; i < 8; ++i) {
        const int row = ty * 8 + i;
        redv1[row * 17 + tx] = rmin1[i];
        redk1[row * 17 + tx] = ridx1[i];
        redv2[row * 17 + tx] = rmin2[i];
    }
    __syncthreads();

    if (t < TOKT) {
        float best1 = 3.4e38f, best2 = 3.4e38f; int bk = CBK;
        #pragma unroll
        for (int j = 0; j < 16; ++j) {
            float v1 = redv1[t * 17 + j];
            int   k1 = redk1[t * 17 + j];
            float v2 = redv2[t * 17 + j];
            if (v1 < best1 || (v1 == best1 && k1 < bk)) {
                best2 = fminf(best2, best1);
                best1 = v1; bk = k1;
                best2 = fminf(best2, v2);
            } else {
                best2 = fminf(best2, v1);
            }
        }
        if (best2 - best1 <= MARGIN) {
            int slot = atomicAdd(&cnt_s, 1);
            flag_s[slot] = t;                       // needs bit-exact rescan
        } else {
            bestk_s[t] = bk;                        // provably chain-argmin
            iout[(size_t)(tok0 + t) * NSUB + m] = (float)bk;
        }
    }
    __syncthreads();

    // ---- pass 2: bit-exact chain rescan for flagged tokens ----
    const int nflag = cnt_s;
    for (int f = 0; f < nflag; ++f) {
        const int tok = flag_s[f];
        float xl[64];
        #pragma unroll
        for (int d = 0; d < 64; ++d) xl[d] = As[d][tok];   // broadcast reads
        const float x2v = x2s[tok];
        float bs = 3.4e38f; int bk = CBK;
        #pragma unroll
        for (int r = 0; r < 4; ++r) {
            const int k = t + 256 * r;                     // ascending per thread
            const float* crow = cb + ((size_t)m * CBK + k) * SDIM;
            float acc = 0.f;
            #pragma unroll
            for (int i = 0; i < 16; ++i) {
                float4 c4 = *(const float4*)(crow + 4 * i);
                acc = __fmaf_rn(xl[4*i+0], c4.x, acc);
                acc = __fmaf_rn(xl[4*i+1], c4.y, acc);
                acc = __fmaf_rn(xl[4*i+2], c4.z, acc);
                acc = __fmaf_rn(xl[4*i+3], c4.w, acc);
            }
            const float dist = fadd(fsub(x2v, fmul(2.0f, acc)), C2[k]);
            if (dist < bs) { bs = dist; bk = k; }
        }
        red_v[t] = bs; red_k[t] = bk;
        __syncthreads();
        for (int off = 128; off > 0; off >>= 1) {
            if (t < off) {
                float o = red_v[t + off]; int ok = red_k[t + off];
                if (o < red_v[t] || (o == red_v[t] && ok < red_k[t])) {
                    red_v[t] = o; red_k[t] = ok;
                }
            }
            __syncthreads();
        }
        if (t == 0) {
            bestk_s[tok] = red_k[0];
            iout[(size_t)(tok0 + tok) * NSUB + m] = (float)red_k[0];
        }
        __syncthreads();
    }

    // ---- gather winning codewords ----
    {
        const int tok = t >> 1, d0 = (t & 1) * 32;
        const int bk  = bestk_s[tok];
        const float* src = cb + ((size_t)m * CBK + bk) * SDIM + d0;
        float* dst = qout + (size_t)(tok0 + tok) * EMB + m * SDIM + d0;
        #pragma unroll
        for (int i = 0; i < 8; ++i)
            *(float4*)(dst + 4 * i) = *(const float4*)(src + 4 * i);
    }
}

extern "C" void kernel_launch(void* const* d_in, const int* in_sizes, int n_in,
                              void* d_out, int out_size, void* d_ws, size_t ws_size,
                              hipStream_t stream) {
    const float* emb = (const float*)d_in[0];   // [8,2048,1024] f32
    const float* cb  = (const float*)d_in[1];   // [16,1024,64] f32
    float* qout = (float*)d_out;                              // [N, EMB] f32
    float* iout = (float*)d_out + (size_t)NTOK * EMB;         // [N, 16] as f32

    dim3 grid(NTOK / TOKT, NSUB);
    pq_twophase_kernel<<<grid, 256, 0, stream>>>(emb, cb, qout, iout);
}

// Round 8
// 335.831 us; speedup vs baseline: 2.2052x; 1.9315x over previous
//
#include <hip/hip_runtime.h>
#include <hip/hip_bf16.h>

// Correctness contract (verified R6/R7, absmax=0):
//   xc   = sequential __fmaf_rn chain over d=0..63 ascending
//   x2,c2= numpy pairwise scalar 8-accumulator scheme
//   dist = fl(fl(x2 - 2*xc) + c2), argmin first-occurrence
// Fast pass: split-bf16 MFMA (xh*ch + xh*cl + xl*ch), |err| << MARGIN.
// Near-ties (gap<=MARGIN) -> bit-exact chain rescan.
#pragma clang fp contract(off)

#define NSUB 16
#define CBK  1024
#define SDIM 64
#define EMB  1024
#define NTOK 16384
#define TOKB 128        // tokens per main block (4 waves x 32)
#define MARGIN 5e-3f

typedef __attribute__((ext_vector_type(8))) short bf16x8;
typedef __attribute__((ext_vector_type(4))) float f32x4;

__device__ __forceinline__ float fmul(float a, float b) { return __fmul_rn(a, b); }
__device__ __forceinline__ float fadd(float a, float b) { return __fadd_rn(a, b); }
__device__ __forceinline__ float fsub(float a, float b) { return __fsub_rn(a, b); }

// numpy pairwise replica (scalar 8-accumulator, n=64), contiguous.
__device__ __forceinline__ float np_sq64(const float* v) {
    float r[8];
    #pragma unroll
    for (int j = 0; j < 8; ++j) r[j] = fmul(v[j], v[j]);
    #pragma unroll
    for (int b = 1; b < 8; ++b) {
        #pragma unroll
        for (int j = 0; j < 8; ++j)
            r[j] = fadd(r[j], fmul(v[b * 8 + j], v[b * 8 + j]));
    }
    return fadd(fadd(fadd(r[0], r[1]), fadd(r[2], r[3])),
                fadd(fadd(r[4], r[5]), fadd(r[6], r[7])));
}

__device__ __forceinline__ void split_bf16(float v, short& hi, short& lo) {
    __hip_bfloat16 h = __float2bfloat16(v);
    float hf = __bfloat162float(h);
    __hip_bfloat16 e = __float2bfloat16(__fsub_rn(v, hf));
    hi = *(short*)&h;
    lo = *(short*)&e;
}

// ---- prep: pack codebook into MFMA B-fragment layout (bf16 hi/lo) + C2 ----
// bpack layout: [m][tc=64][c=2][part=2][lane=64][j=8] bf16  (4 MB)
__global__ __launch_bounds__(256)
void prep_kernel(const float* __restrict__ cb,
                 unsigned short* __restrict__ bpack,
                 float* __restrict__ c2g)
{
    const int bx = blockIdx.x;   // 0..15
    const int m  = blockIdx.y;   // 0..15
    const int t  = threadIdx.x;
    const int w  = t >> 6, l = t & 63;
    const int tc = bx * 4 + w;                 // tile-col 0..63
    const int cw = tc * 16 + (l & 15);
    const int dq = (l >> 4) * 8;

    #pragma unroll
    for (int c = 0; c < 2; ++c) {
        const float* src = cb + ((size_t)m * CBK + cw) * SDIM + c * 32 + dq;
        unsigned short hi[8], lo[8];
        #pragma unroll
        for (int j = 0; j < 8; ++j) {
            short h, e; split_bf16(src[j], h, e);
            hi[j] = (unsigned short)h; lo[j] = (unsigned short)e;
        }
        size_t base = ((((size_t)m * 64 + tc) * 2 + c) * 2) * 512 + (size_t)l * 8;
        #pragma unroll
        for (int j = 0; j < 8; ++j) bpack[base + j] = hi[j];
        #pragma unroll
        for (int j = 0; j < 8; ++j) bpack[base + 512 + j] = lo[j];
    }
    if (t < 64) {
        const int row = bx * 64 + t;
        c2g[m * CBK + row] = np_sq64(cb + ((size_t)m * CBK + row) * SDIM);
    }
}

// ---- main: MFMA fast pass + exact-chain fallback ----
__global__ __launch_bounds__(256)
void pq_mfma_kernel(const float* __restrict__ emb,
                    const float* __restrict__ cb,
                    const unsigned short* __restrict__ bpack,
                    const float* __restrict__ c2g,
                    float* __restrict__ qout,
                    float* __restrict__ iout)
{
    __shared__ unsigned short Bsh[16384];   // 32 KB: [tc_local=8][c=2][part=2][512]
    __shared__ float C2s[CBK];              // 4 KB replica ||c||^2
    __shared__ float red_v[256];
    __shared__ int   red_k[256];
    __shared__ int   bestk_s[TOKB];
    __shared__ int   flag_s[TOKB];
    __shared__ int   cnt_s;

    const int m = blockIdx.y, tok0 = blockIdx.x * TOKB;
    const int t = threadIdx.x, w = t >> 6, l = t & 63;
    const int ln15 = l & 15, q = l >> 4;

    if (t == 0) cnt_s = 0;
    *(f32x4*)(C2s + t * 4) = *(const f32x4*)(c2g + m * CBK + t * 4);

    // x fragments (A-operand layout: m=lane&15, k=(lane>>4)*8+j), split hi/lo
    bf16x8 xh[2][2], xl[2][2];
    #pragma unroll
    for (int r = 0; r < 2; ++r) {
        const int tok = tok0 + w * 32 + r * 16 + ln15;
        #pragma unroll
        for (int c = 0; c < 2; ++c) {
            const float* src = emb + (size_t)tok * EMB + m * SDIM + c * 32 + q * 8;
            float4 v0 = *(const float4*)(src);
            float4 v1 = *(const float4*)(src + 4);
            float vv[8] = {v0.x,v0.y,v0.z,v0.w,v1.x,v1.y,v1.z,v1.w};
            #pragma unroll
            for (int j = 0; j < 8; ++j) {
                short h, e; split_bf16(vv[j], h, e);
                xh[r][c][j] = h; xl[r][c][j] = e;
            }
        }
    }

    float v1t[2][4], v2t[2][4]; int k1t[2][4];
    #pragma unroll
    for (int r = 0; r < 2; ++r)
        #pragma unroll
        for (int g = 0; g < 4; ++g) { v1t[r][g] = 3.4e38f; v2t[r][g] = 3.4e38f; k1t[r][g] = 0; }

    for (int ch = 0; ch < 8; ++ch) {
        __syncthreads();
        // stage 32 KB B-chunk via async global->LDS (16B/lane, coalesced)
        {
            const char* gsrc = (const char*)bpack + ((size_t)m * 64 + ch * 8) * 4096;
            #pragma unroll
            for (int i = 0; i < 8; ++i) {
                __builtin_amdgcn_global_load_lds(
                    (const __attribute__((address_space(1))) unsigned int*)
                        (gsrc + i * 4096 + w * 1024 + l * 16),
                    (__attribute__((address_space(3))) unsigned int*)
                        ((char*)Bsh + i * 4096 + w * 1024),
                    16, 0, 0);
            }
        }
        __syncthreads();

        for (int tcl = 0; tcl < 8; ++tcl) {
            const unsigned short* bb = Bsh + tcl * 2048;
            bf16x8 bh0 = *(const bf16x8*)(bb + l * 8);
            bf16x8 bl0 = *(const bf16x8*)(bb + 512 + l * 8);
            bf16x8 bh1 = *(const bf16x8*)(bb + 1024 + l * 8);
            bf16x8 bl1 = *(const bf16x8*)(bb + 1536 + l * 8);
            const int kk = (ch * 8 + tcl) * 16 + ln15;
            const float c2v = C2s[kk];
            #pragma unroll
            for (int r = 0; r < 2; ++r) {
                f32x4 acc = {0.f, 0.f, 0.f, 0.f};
                acc = __builtin_amdgcn_mfma_f32_16x16x32_bf16(xh[r][0], bh0, acc, 0, 0, 0);
                acc = __builtin_amdgcn_mfma_f32_16x16x32_bf16(xh[r][1], bh1, acc, 0, 0, 0);
                acc = __builtin_amdgcn_mfma_f32_16x16x32_bf16(xl[r][0], bh0, acc, 0, 0, 0);
                acc = __builtin_amdgcn_mfma_f32_16x16x32_bf16(xl[r][1], bh1, acc, 0, 0, 0);
                acc = __builtin_amdgcn_mfma_f32_16x16x32_bf16(xh[r][0], bl0, acc, 0, 0, 0);
                acc = __builtin_amdgcn_mfma_f32_16x16x32_bf16(xh[r][1], bl1, acc, 0, 0, 0);
                #pragma unroll
                for (int g = 0; g < 4; ++g) {
                    float s = __fmaf_rn(-2.f, acc[g], c2v);
                    bool lt = s < v1t[r][g];
                    v2t[r][g] = fminf(fmaxf(s, v1t[r][g]), v2t[r][g]);
                    v1t[r][g] = lt ? s : v1t[r][g];
                    k1t[r][g] = lt ? kk : k1t[r][g];
                }
            }
        }
    }
    __syncthreads();

    // merge top-2 across the 16 lanes sharing each token (C/D row = q*4+g)
    #pragma unroll
    for (int r = 0; r < 2; ++r) {
        #pragma unroll
        for (int g = 0; g < 4; ++g) {
            float v1 = v1t[r][g], v2 = v2t[r][g]; int k1 = k1t[r][g];
            #pragma unroll
            for (int mask = 1; mask < 16; mask <<= 1) {
                float ov1 = __shfl_xor(v1, mask);
                float ov2 = __shfl_xor(v2, mask);
                int   ok1 = __shfl_xor(k1, mask);
                if (ov1 < v1 || (ov1 == v1 && ok1 < k1)) {
                    v2 = fminf(v1, ov2);
                    v1 = ov1; k1 = ok1;
                } else {
                    v2 = fminf(v2, ov1);
                }
            }
            if (ln15 == 0) {
                const int token = w * 32 + r * 16 + q * 4 + g;
                if (v2 - v1 <= MARGIN) {
                    int slot = atomicAdd(&cnt_s, 1);
                    flag_s[slot] = token;
                } else {
                    bestk_s[token] = k1;
                    iout[(size_t)(tok0 + token) * NSUB + m] = (float)k1;
                }
            }
        }
    }
    __syncthreads();

    // ---- pass 2: bit-exact chain rescan for flagged tokens ----
    const int nflag = cnt_s;
    for (int f = 0; f < nflag; ++f) {
        const int token = flag_s[f];
        const float* xrow = emb + (size_t)(tok0 + token) * EMB + m * SDIM;
        const float x2v = np_sq64(xrow);          // broadcast reads, L1-hot
        float bs = 3.4e38f; int bk = CBK;
        #pragma unroll
        for (int rr = 0; rr < 4; ++rr) {
            const int k = t + 256 * rr;           // ascending per thread
            const float* crow = cb + ((size_t)m * CBK + k) * SDIM;
            float acc = 0.f;
            #pragma unroll
            for (int i = 0; i < 16; ++i) {
                float4 c4 = *(const float4*)(crow + 4 * i);
                float4 x4 = *(const float4*)(xrow + 4 * i);
                acc = __fmaf_rn(x4.x, c4.x, acc);
                acc = __fmaf_rn(x4.y, c4.y, acc);
                acc = __fmaf_rn(x4.z, c4.z, acc);
                acc = __fmaf_rn(x4.w, c4.w, acc);
            }
            const float dist = fadd(fsub(x2v, fmul(2.f, acc)), C2s[k]);
            if (dist < bs) { bs = dist; bk = k; }
        }
        red_v[t] = bs; red_k[t] = bk;
        __syncthreads();
        for (int off = 128; off > 0; off >>= 1) {
            if (t < off) {
                float o = red_v[t + off]; int ok = red_k[t + off];
                if (o < red_v[t] || (o == red_v[t] && ok < red_k[t])) {
                    red_v[t] = o; red_k[t] = ok;
                }
            }
            __syncthreads();
        }
        if (t == 0) {
            bestk_s[token] = red_k[0];
            iout[(size_t)(tok0 + token) * NSUB + m] = (float)red_k[0];
        }
        __syncthreads();
    }

    // ---- gather winning codewords ----
    {
        const int tok = t >> 1, d0 = (t & 1) * 32;
        const int bk  = bestk_s[tok];
        const float* src = cb + ((size_t)m * CBK + bk) * SDIM + d0;
        float* dst = qout + (size_t)(tok0 + tok) * EMB + m * SDIM + d0;
        #pragma unroll
        for (int i = 0; i < 8; ++i)
            *(float4*)(dst + 4 * i) = *(const float4*)(src + 4 * i);
    }
}

extern "C" void kernel_launch(void* const* d_in, const int* in_sizes, int n_in,
                              void* d_out, int out_size, void* d_ws, size_t ws_size,
                              hipStream_t stream) {
    const float* emb = (const float*)d_in[0];   // [8,2048,1024] f32
    const float* cb  = (const float*)d_in[1];   // [16,1024,64] f32
    float* qout = (float*)d_out;                              // [N, EMB] f32
    float* iout = (float*)d_out + (size_t)NTOK * EMB;         // [N, 16] as f32

    unsigned short* bpack = (unsigned short*)d_ws;            // 4 MB
    float* c2g = (float*)((char*)d_ws + 4u * 1024u * 1024u);  // 64 KB

    prep_kernel<<<dim3(16, 16), 256, 0, stream>>>(cb, bpack, c2g);
    pq_mfma_kernel<<<dim3(NTOK / TOKB, NSUB), 256, 0, stream>>>(
        emb, cb, bpack, c2g, qout, iout);
}

// Round 9
// 288.039 us; speedup vs baseline: 2.5711x; 1.1659x over previous
//
#include <hip/hip_runtime.h>
#include <hip/hip_bf16.h>

// Correctness contract (verified R6-R8, absmax=0):
//   xc   = sequential __fmaf_rn chain over d=0..63 ascending
//   x2,c2= numpy pairwise scalar 8-accumulator scheme
//   dist = fl(fl(x2 - 2*xc) + c2), argmin first-occurrence
// Fast pass: split-bf16 MFMA on (-2c) with C2-initialized accumulator;
// |fast - exact| << MARGIN. Near-ties (gap<=MARGIN) -> bit-exact rescan.
#pragma clang fp contract(off)

#define NSUB 16
#define CBK  1024
#define SDIM 64
#define EMB  1024
#define NTOK 16384
#define TOKB 128
#define MARGIN 5e-3f

typedef __attribute__((ext_vector_type(8))) short bf16x8;
typedef __attribute__((ext_vector_type(4))) float f32x4;

__device__ __forceinline__ float fmul(float a, float b) { return __fmul_rn(a, b); }
__device__ __forceinline__ float fadd(float a, float b) { return __fadd_rn(a, b); }
__device__ __forceinline__ float fsub(float a, float b) { return __fsub_rn(a, b); }

// numpy pairwise replica (scalar 8-accumulator, n=64), contiguous.
__device__ __forceinline__ float np_sq64(const float* v) {
    float r[8];
    #pragma unroll
    for (int j = 0; j < 8; ++j) r[j] = fmul(v[j], v[j]);
    #pragma unroll
    for (int b = 1; b < 8; ++b) {
        #pragma unroll
        for (int j = 0; j < 8; ++j)
            r[j] = fadd(r[j], fmul(v[b * 8 + j], v[b * 8 + j]));
    }
    return fadd(fadd(fadd(r[0], r[1]), fadd(r[2], r[3])),
                fadd(fadd(r[4], r[5]), fadd(r[6], r[7])));
}

__device__ __forceinline__ void split_bf16(float v, short& hi, short& lo) {
    __hip_bfloat16 h = __float2bfloat16(v);
    float hf = __bfloat162float(h);
    __hip_bfloat16 e = __float2bfloat16(__fsub_rn(v, hf));
    hi = *(short*)&h;
    lo = *(short*)&e;
}

// ---- prep: pack (-2*codebook) into MFMA B-fragment layout (bf16 hi/lo) + C2 ----
// bpack layout: [m][tc=64][c=2][part=2][lane=64][j=8] bf16  (4 MB)
__global__ __launch_bounds__(256)
void prep_kernel(const float* __restrict__ cb,
                 unsigned short* __restrict__ bpack,
                 float* __restrict__ c2g)
{
    const int bx = blockIdx.x;   // 0..15
    const int m  = blockIdx.y;   // 0..15
    const int t  = threadIdx.x;
    const int w  = t >> 6, l = t & 63;
    const int tc = bx * 4 + w;                 // tile-col 0..63
    const int cw = tc * 16 + (l & 15);
    const int dq = (l >> 4) * 8;

    #pragma unroll
    for (int c = 0; c < 2; ++c) {
        const float* src = cb + ((size_t)m * CBK + cw) * SDIM + c * 32 + dq;
        bf16x8 hv, lv;
        #pragma unroll
        for (int j = 0; j < 8; ++j) {
            short h, e; split_bf16(-2.0f * src[j], h, e);  // -2x exact in fp32
            hv[j] = h; lv[j] = e;
        }
        size_t base = (((size_t)(m * 64 + tc) * 2 + c) * 2) * 512 + (size_t)l * 8;
        *(bf16x8*)(bpack + base)       = hv;   // 16B vector stores, coalesced
        *(bf16x8*)(bpack + base + 512) = lv;
    }
    if (t < 64) {
        const int row = bx * 64 + t;
        c2g[m * CBK + row] = np_sq64(cb + ((size_t)m * CBK + row) * SDIM);
    }
}

// ---- main: MFMA fast pass (B direct from L2, ping-pong prefetch) ----
__global__ __launch_bounds__(256, 3)
void pq_mfma_kernel(const float* __restrict__ emb,
                    const float* __restrict__ cb,
                    const unsigned short* __restrict__ bpack,
                    const float* __restrict__ c2g,
                    float* __restrict__ qout,
                    float* __restrict__ iout)
{
    __shared__ float C2s[CBK];              // 4 KB replica ||c||^2
    __shared__ float red_v[256];
    __shared__ int   red_k[256];
    __shared__ int   bestk_s[TOKB];
    __shared__ int   flag_s[TOKB];
    __shared__ int   cnt_s;

    const int m = blockIdx.y, tok0 = blockIdx.x * TOKB;
    const int t = threadIdx.x, w = t >> 6, l = t & 63;
    const int ln15 = l & 15, q = l >> 4;

    if (t == 0) cnt_s = 0;
    *(f32x4*)(C2s + t * 4) = *(const f32x4*)(c2g + m * CBK + t * 4);

    // x fragments (A-operand: row=lane&15, k=(lane>>4)*8+j), split hi/lo
    bf16x8 xh[2][2], xl[2][2];
    #pragma unroll
    for (int r = 0; r < 2; ++r) {
        const int tok = tok0 + w * 32 + r * 16 + ln15;
        #pragma unroll
        for (int c = 0; c < 2; ++c) {
            const float* src = emb + (size_t)tok * EMB + m * SDIM + c * 32 + q * 8;
            float4 v0 = *(const float4*)(src);
            float4 v1 = *(const float4*)(src + 4);
            float vv[8] = {v0.x,v0.y,v0.z,v0.w,v1.x,v1.y,v1.z,v1.w};
            #pragma unroll
            for (int j = 0; j < 8; ++j) {
                short h, e; split_bf16(vv[j], h, e);
                xh[r][c][j] = h; xl[r][c][j] = e;
            }
        }
    }
    __syncthreads();   // C2s ready

    float v1t[2][4], v2t[2][4]; int k1t[2][4];
    #pragma unroll
    for (int r = 0; r < 2; ++r)
        #pragma unroll
        for (int g = 0; g < 4; ++g) { v1t[r][g] = 3.4e38f; v2t[r][g] = 3.4e38f; k1t[r][g] = 0; }

    // B fragments straight from global (L2-resident, already fragment-ordered)
    const unsigned short* bptr = bpack + (size_t)m * 64 * 2048 + (size_t)l * 8;
    bf16x8 A0 = *(const bf16x8*)(bptr);
    bf16x8 A1 = *(const bf16x8*)(bptr + 512);
    bf16x8 A2 = *(const bf16x8*)(bptr + 1024);
    bf16x8 A3 = *(const bf16x8*)(bptr + 1536);

#define COMPUTE_TILE(B0, B1, B2, B3, TC)                                        \
    {                                                                           \
        const int kk = (TC) * 16 + ln15;                                        \
        const float c2v = C2s[kk];                                              \
        _Pragma("unroll")                                                       \
        for (int r = 0; r < 2; ++r) {                                           \
            f32x4 acc = {c2v, c2v, c2v, c2v};                                   \
            acc = __builtin_amdgcn_mfma_f32_16x16x32_bf16(xh[r][0], B0, acc, 0, 0, 0); \
            acc = __builtin_amdgcn_mfma_f32_16x16x32_bf16(xh[r][1], B2, acc, 0, 0, 0); \
            acc = __builtin_amdgcn_mfma_f32_16x16x32_bf16(xl[r][0], B0, acc, 0, 0, 0); \
            acc = __builtin_amdgcn_mfma_f32_16x16x32_bf16(xl[r][1], B2, acc, 0, 0, 0); \
            acc = __builtin_amdgcn_mfma_f32_16x16x32_bf16(xh[r][0], B1, acc, 0, 0, 0); \
            acc = __builtin_amdgcn_mfma_f32_16x16x32_bf16(xh[r][1], B3, acc, 0, 0, 0); \
            _Pragma("unroll")                                                   \
            for (int g = 0; g < 4; ++g) {                                       \
                float s = acc[g];                                               \
                v2t[r][g] = fminf(v2t[r][g], fmaxf(s, v1t[r][g]));              \
                bool lt = s < v1t[r][g];                                        \
                v1t[r][g] = lt ? s : v1t[r][g];                                 \
                k1t[r][g] = lt ? kk : k1t[r][g];                                \
            }                                                                   \
        }                                                                       \
    }

    for (int tc = 0; tc < 64; tc += 2) {
        const unsigned short* p1 = bptr + (size_t)(tc + 1) * 2048;
        bf16x8 N0 = *(const bf16x8*)(p1);
        bf16x8 N1 = *(const bf16x8*)(p1 + 512);
        bf16x8 N2 = *(const bf16x8*)(p1 + 1024);
        bf16x8 N3 = *(const bf16x8*)(p1 + 1536);
        COMPUTE_TILE(A0, A1, A2, A3, tc)
        if (tc + 2 < 64) {
            const unsigned short* p2 = bptr + (size_t)(tc + 2) * 2048;
            A0 = *(const bf16x8*)(p2);
            A1 = *(const bf16x8*)(p2 + 512);
            A2 = *(const bf16x8*)(p2 + 1024);
            A3 = *(const bf16x8*)(p2 + 1536);
        }
        COMPUTE_TILE(N0, N1, N2, N3, tc + 1)
    }
#undef COMPUTE_TILE
    __syncthreads();

    // merge top-2 across the 16 lanes sharing each token (C/D row = q*4+g)
    #pragma unroll
    for (int r = 0; r < 2; ++r) {
        #pragma unroll
        for (int g = 0; g < 4; ++g) {
            float v1 = v1t[r][g], v2 = v2t[r][g]; int k1 = k1t[r][g];
            #pragma unroll
            for (int mask = 1; mask < 16; mask <<= 1) {
                float ov1 = __shfl_xor(v1, mask);
                float ov2 = __shfl_xor(v2, mask);
                int   ok1 = __shfl_xor(k1, mask);
                if (ov1 < v1 || (ov1 == v1 && ok1 < k1)) {
                    v2 = fminf(v1, ov2);
                    v1 = ov1; k1 = ok1;
                } else {
                    v2 = fminf(v2, ov1);
                }
            }
            if (ln15 == 0) {
                const int token = w * 32 + r * 16 + q * 4 + g;
                if (v2 - v1 <= MARGIN) {
                    int slot = atomicAdd(&cnt_s, 1);
                    flag_s[slot] = token;
                } else {
                    bestk_s[token] = k1;
                    iout[(size_t)(tok0 + token) * NSUB + m] = (float)k1;
                }
            }
        }
    }
    __syncthreads();

    // ---- pass 2: bit-exact chain rescan for flagged tokens ----
    const int nflag = cnt_s;
    for (int f = 0; f < nflag; ++f) {
        const int token = flag_s[f];
        const float* xrow = emb + (size_t)(tok0 + token) * EMB + m * SDIM;
        const float x2v = np_sq64(xrow);          // broadcast reads, L1-hot
        float bs = 3.4e38f; int bk = CBK;
        #pragma unroll
        for (int rr = 0; rr < 4; ++rr) {
            const int k = t + 256 * rr;           // ascending per thread
            const float* crow = cb + ((size_t)m * CBK + k) * SDIM;
            float acc = 0.f;
            #pragma unroll
            for (int i = 0; i < 16; ++i) {
                float4 c4 = *(const float4*)(crow + 4 * i);
                float4 x4 = *(const float4*)(xrow + 4 * i);
                acc = __fmaf_rn(x4.x, c4.x, acc);
                acc = __fmaf_rn(x4.y, c4.y, acc);
                acc = __fmaf_rn(x4.z, c4.z, acc);
                acc = __fmaf_rn(x4.w, c4.w, acc);
            }
            const float dist = fadd(fsub(x2v, fmul(2.f, acc)), C2s[k]);
            if (dist < bs) { bs = dist; bk = k; }
        }
        red_v[t] = bs; red_k[t] = bk;
        __syncthreads();
        for (int off = 128; off > 0; off >>= 1) {
            if (t < off) {
                float o = red_v[t + off]; int ok = red_k[t + off];
                if (o < red_v[t] || (o == red_v[t] && ok < red_k[t])) {
                    red_v[t] = o; red_k[t] = ok;
                }
            }
            __syncthreads();
        }
        if (t == 0) {
            bestk_s[token] = red_k[0];
            iout[(size_t)(tok0 + token) * NSUB + m] = (float)red_k[0];
        }
        __syncthreads();
    }

    // ---- gather winning codewords ----
    {
        const int tok = t >> 1, d0 = (t & 1) * 32;
        const int bk  = bestk_s[tok];
        const float* src = cb + ((size_t)m * CBK + bk) * SDIM + d0;
        float* dst = qout + (size_t)(tok0 + tok) * EMB + m * SDIM + d0;
        #pragma unroll
        for (int i = 0; i < 8; ++i)
            *(float4*)(dst + 4 * i) = *(const float4*)(src + 4 * i);
    }
}

extern "C" void kernel_launch(void* const* d_in, const int* in_sizes, int n_in,
                              void* d_out, int out_size, void* d_ws, size_t ws_size,
                              hipStream_t stream) {
    const float* emb = (const float*)d_in[0];   // [8,2048,1024] f32
    const float* cb  = (const float*)d_in[1];   // [16,1024,64] f32
    float* qout = (float*)d_out;                              // [N, EMB] f32
    float* iout = (float*)d_out + (size_t)NTOK * EMB;         // [N, 16] as f32

    unsigned short* bpack = (unsigned short*)d_ws;            // 4 MB
    float* c2g = (float*)((char*)d_ws + 4u * 1024u * 1024u);  // 64 KB

    prep_kernel<<<dim3(16, 16), 256, 0, stream>>>(cb, bpack, c2g);
    pq_mfma_kernel<<<dim3(NTOK / TOKB, NSUB), 256, 0, stream>>>(
        emb, cb, bpack, c2g, qout, iout);
}